// Round 2
// 4175.415 us; speedup vs baseline: 1.6925x; 1.6925x over previous
//
#include <hip/hip_runtime.h>

#define HIDDEN 3072
#define NHEADS 24
#define HDIM   128
#define MLPD   12288
#define RANK   32
#define TXTL   512
#define IMGL   2048
#define SEQL   2560

typedef __bf16 bf16;
typedef __attribute__((ext_vector_type(8))) __bf16 bf16x8;
typedef __attribute__((ext_vector_type(4))) __bf16 bf16x4;
typedef __attribute__((ext_vector_type(2))) __bf16 bf16x2;
typedef __attribute__((ext_vector_type(4))) float  f32x4;

// ---------------------------------------------------------------- helpers
__device__ __forceinline__ void async_copy16(const void* gsrc, void* ldst) {
    __builtin_amdgcn_global_load_lds(
        (const __attribute__((address_space(1))) void*)gsrc,
        (__attribute__((address_space(3))) void*)ldst, 16, 0, 0);
}

__device__ __forceinline__ float gelu_tanh(float x) {
    float x3 = x * x * x;
    float z  = 0.7978845608028654f * (x + 0.044715f * x3);
    z = fminf(fmaxf(z, -15.f), 15.f);
    float e  = __expf(2.f * z);
    float th = (e - 1.f) / (e + 1.f);
    return 0.5f * x * (1.f + th);
}

// ---------------------------------------------------------------- GEMM
// C[M x N] (f32) = A[M x K] (bf16, row-major) @ B[N x K]^T (f32, row-major)
// 128x128 tile, BK=32, 4 waves (2x2), 16x16x32 bf16 MFMA, 4x4 frags/wave.
// A staged via global_load_lds (width 16). B staged through REGISTERS:
// f32 global load -> bf16 convert (once per element) -> ds_write_b128 into a
// bf16 [128][32] LDS tile. 64B row stride => fragment ds_read_b128 sits at
// the 8-cycle wave64 floor (conflict-free); thread-linear ds_write is linear.
// This replaces the old f32 [128][32] Bs (128B stride, 16-way read conflicts,
// 4.2e8 SQ_LDS_BANK_CONFLICT) and the per-fragment redundant f32->bf16 cvt.
// ACC=true: C += (used for the rank-32 LoRA update, K=32).
template<bool ACC>
__global__ __launch_bounds__(256) void gemm_bt(const bf16* __restrict__ A,
                                               const float* __restrict__ B,
                                               float* __restrict__ C,
                                               int M, int N, int K)
{
    __shared__ bf16 As[128 * 32];
    __shared__ bf16 Bs[128 * 32];
    const int t    = threadIdx.x;
    const int wave = t >> 6, lane = t & 63;
    const int lm   = lane & 15, lq = lane >> 4;
    const int wy   = wave >> 1, wx = wave & 1;
    const int m0   = blockIdx.y * 128, n0 = blockIdx.x * 128;

    // element offsets for 2 staging rounds (256 threads x 8 elems each)
    const int f0 = t * 8;
    const int f1 = 2048 + t * 8;
    const bf16*  aG0 = A + (size_t)(m0 + (f0 >> 5)) * K + (f0 & 31);
    const bf16*  aG1 = A + (size_t)(m0 + (f1 >> 5)) * K + (f1 & 31);
    const float* bG0 = B + (size_t)(n0 + (f0 >> 5)) * K + (f0 & 31);
    const float* bG1 = B + (size_t)(n0 + (f1 >> 5)) * K + (f1 & 31);
    bf16* aL0 = As + wave * 512;          // wave-uniform LDS dest (lane*16B implicit)
    bf16* aL1 = As + 2048 + wave * 512;
    bf16* bW0 = Bs + f0;                  // thread-linear ds_write dest
    bf16* bW1 = Bs + f1;

    f32x4 acc[4][4];
#pragma unroll
    for (int i = 0; i < 4; ++i)
#pragma unroll
        for (int j = 0; j < 4; ++j)
            acc[i][j] = (f32x4){0.f, 0.f, 0.f, 0.f};

    for (int k0 = 0; k0 < K; k0 += 32) {
        async_copy16(aG0 + k0, aL0);
        async_copy16(aG1 + k0, aL1);
        {
            float4 x0 = *(const float4*)(bG0 + k0);
            float4 x1 = *(const float4*)(bG0 + k0 + 4);
            float4 y0 = *(const float4*)(bG1 + k0);
            float4 y1 = *(const float4*)(bG1 + k0 + 4);
            bf16x8 b0, b1;
            b0[0] = (bf16)x0.x; b0[1] = (bf16)x0.y; b0[2] = (bf16)x0.z; b0[3] = (bf16)x0.w;
            b0[4] = (bf16)x1.x; b0[5] = (bf16)x1.y; b0[6] = (bf16)x1.z; b0[7] = (bf16)x1.w;
            b1[0] = (bf16)y0.x; b1[1] = (bf16)y0.y; b1[2] = (bf16)y0.z; b1[3] = (bf16)y0.w;
            b1[4] = (bf16)y1.x; b1[5] = (bf16)y1.y; b1[6] = (bf16)y1.z; b1[7] = (bf16)y1.w;
            *(bf16x8*)bW0 = b0;
            *(bf16x8*)bW1 = b1;
        }
        __syncthreads();   // drains global_load_lds (vmcnt) + ds_write (lgkmcnt)

        bf16x8 af[4], bfm[4];
#pragma unroll
        for (int mi = 0; mi < 4; ++mi)
            af[mi] = *(const bf16x8*)(As + (wy * 64 + mi * 16 + lm) * 32 + lq * 8);
#pragma unroll
        for (int ni = 0; ni < 4; ++ni)
            bfm[ni] = *(const bf16x8*)(Bs + (wx * 64 + ni * 16 + lm) * 32 + lq * 8);
#pragma unroll
        for (int ni = 0; ni < 4; ++ni)
#pragma unroll
            for (int mi = 0; mi < 4; ++mi)
                acc[mi][ni] = __builtin_amdgcn_mfma_f32_16x16x32_bf16(af[mi], bfm[ni], acc[mi][ni], 0, 0, 0);
        __syncthreads();
    }

#pragma unroll
    for (int mi = 0; mi < 4; ++mi)
#pragma unroll
        for (int ni = 0; ni < 4; ++ni)
#pragma unroll
            for (int r = 0; r < 4; ++r) {
                int row = m0 + wy * 64 + mi * 16 + lq * 4 + r;   // C-layout: row=(lane>>4)*4+reg
                int col = n0 + wx * 64 + ni * 16 + lm;           // col=lane&15  [m89/m91-verified]
                size_t idx = (size_t)row * N + col;
                if (ACC) C[idx] += acc[mi][ni][r];
                else     C[idx]  = acc[mi][ni][r];
            }
}

// ---------------------------------------------------------------- modulation GEMV
// mods[2*18432] = silu(vec) @ mod_w^T + mod_b  (memory-bound: 453 MB of mod_w)
__global__ __launch_bounds__(256) void mod_gemv(const float* __restrict__ vec,
                                                const float* __restrict__ mod_w,
                                                const float* __restrict__ mod_b,
                                                float* __restrict__ mods)
{
    __shared__ float svs[HIDDEN];
    const int t = threadIdx.x;
    for (int i = t; i < HIDDEN; i += 256) {
        float x = vec[i];
        svs[i] = x / (1.f + __expf(-x));
    }
    __syncthreads();
    const int wave = t >> 6, lane = t & 63;
    const int j = blockIdx.x * 4 + wave;
    const float* wr = mod_w + (size_t)j * HIDDEN;
    float acc = 0.f;
    for (int k = lane * 4; k < HIDDEN; k += 256) {
        float4 wv = *(const float4*)(wr + k);
        float4 s4 = *(const float4*)(svs + k);
        acc += wv.x * s4.x + wv.y * s4.y + wv.z * s4.z + wv.w * s4.w;
    }
#pragma unroll
    for (int off = 1; off < 64; off <<= 1) acc += __shfl_xor(acc, off);
    if (lane == 0) mods[j] = acc + mod_b[j];
}

// ---------------------------------------------------------------- LayerNorm + modulation
// out(bf16) = LN(x_row) * (1+sc) + sh
__global__ __launch_bounds__(256) void ln_mod_k(const float* __restrict__ x,
                                                const float* __restrict__ sc,
                                                const float* __restrict__ sh,
                                                bf16* __restrict__ out)
{
    const int row = blockIdx.x, t = threadIdx.x;
    const int wave = t >> 6, lane = t & 63;
    const float* xr = x + (size_t)row * HIDDEN;
    float v[12];
    float s = 0.f;
#pragma unroll
    for (int i = 0; i < 12; ++i) { v[i] = xr[t + 256 * i]; s += v[i]; }
#pragma unroll
    for (int off = 1; off < 64; off <<= 1) s += __shfl_xor(s, off);
    __shared__ float red[8];
    if (lane == 0) red[wave] = s;
    __syncthreads();
    const float mean = (red[0] + red[1] + red[2] + red[3]) * (1.f / HIDDEN);
    float s2 = 0.f;
#pragma unroll
    for (int i = 0; i < 12; ++i) { float d = v[i] - mean; s2 += d * d; }
#pragma unroll
    for (int off = 1; off < 64; off <<= 1) s2 += __shfl_xor(s2, off);
    if (lane == 0) red[4 + wave] = s2;
    __syncthreads();
    const float var  = (red[4] + red[5] + red[6] + red[7]) * (1.f / HIDDEN);
    const float rstd = rsqrtf(var + 1e-6f);
    bf16* orow = out + (size_t)row * HIDDEN;
#pragma unroll
    for (int i = 0; i < 12; ++i) {
        int jj = t + 256 * i;
        orow[jj] = (bf16)((v[i] - mean) * rstd * (1.f + sc[jj]) + sh[jj]);
    }
}

// ---------------------------------------------------------------- LoRA down: part[split] = A @ ld (chunk of K)
__global__ __launch_bounds__(256) void lora_down(const bf16* __restrict__ A,
                                                 const float* __restrict__ ld,
                                                 float* __restrict__ part,
                                                 int K, int l)
{
    const int t = threadIdx.x;
    const int i = blockIdx.x * 8 + (t >> 5);
    const int r = t & 31;
    const int kchunk = K >> 2;
    const int ks = blockIdx.y * kchunk, ke = ks + kchunk;
    const bf16* ar = A + (size_t)i * K;
    float acc = 0.f;
#pragma unroll 8
    for (int k = ks; k < ke; ++k)
        acc += (float)ar[k] * ld[(size_t)k * RANK + r];
    part[(size_t)blockIdx.y * l * RANK + (size_t)i * RANK + r] = acc;
}

__global__ __launch_bounds__(256) void lora_reduce(const float* __restrict__ part,
                                                   bf16* __restrict__ T, int n)
{
    const int idx = blockIdx.x * 256 + threadIdx.x;
    T[idx] = (bf16)(part[idx] + part[n + idx] + part[2 * n + idx] + part[3 * n + idx]);
}

// ---------------------------------------------------------------- lu (32 x N, f32) -> luT (N x 32, f32)
__global__ __launch_bounds__(256) void transpose_lu(const float* __restrict__ lu,
                                                    float* __restrict__ luT, int N)
{
    const int j = blockIdx.x * 256 + threadIdx.x;
    float v[32];
#pragma unroll
    for (int r = 0; r < 32; ++r) v[r] = lu[(size_t)r * N + j];
#pragma unroll
    for (int r = 0; r < 32; r += 4) {
        float4 o = {v[r], v[r + 1], v[r + 2], v[r + 3]};
        *(float4*)(luT + (size_t)j * 32 + r) = o;
    }
}

// ---------------------------------------------------------------- bf16 transpose (R x C -> C x R), 64x64 tiles
__global__ __launch_bounds__(256) void transpose_v(const bf16* __restrict__ in,
                                                   bf16* __restrict__ out, int R, int Cn)
{
    __shared__ bf16 tile[64][72];
    const int t  = threadIdx.x;
    const int r0 = blockIdx.y * 64, c0 = blockIdx.x * 64;
    const int tr = t >> 4, tc = (t & 15) * 4;
#pragma unroll
    for (int p = 0; p < 4; ++p) {
        int row = p * 16 + tr;
        *(bf16x4*)&tile[row][tc] = *(const bf16x4*)(in + (size_t)(r0 + row) * Cn + c0 + tc);
    }
    __syncthreads();
#pragma unroll
    for (int p = 0; p < 4; ++p) {
        int row = p * 16 + tr;
        bf16x4 v4;
        v4[0] = tile[tc + 0][row];
        v4[1] = tile[tc + 1][row];
        v4[2] = tile[tc + 2][row];
        v4[3] = tile[tc + 3][row];
        *(bf16x4*)(out + (size_t)(c0 + row) * R + r0 + tc) = v4;
    }
}

// ---------------------------------------------------------------- qkv epilogue: +bias, per-head RMS, RoPE, bf16 concat
__global__ __launch_bounds__(256) void qkv_finish(const float* __restrict__ C,
                                                  const float* __restrict__ bias,
                                                  const float* __restrict__ rq,
                                                  const float* __restrict__ rk,
                                                  const float* __restrict__ pe,
                                                  bf16* __restrict__ qc,
                                                  bf16* __restrict__ kc,
                                                  bf16* __restrict__ vc,
                                                  int pos0)
{
    const int t = threadIdx.x, wave = t >> 6, lane = t & 63;
    const int g = blockIdx.x * 4 + wave;
    const int i = g / NHEADS, h = g - i * NHEADS;
    const int pos = pos0 + i;
    const float* cr = C + (size_t)i * (3 * HIDDEN);
    const int cq = h * HDIM + 2 * lane;

    float2 qv = *(const float2*)(cr + cq);
    float2 qb = *(const float2*)(bias + cq);
    float2 kv = *(const float2*)(cr + HIDDEN + cq);
    float2 kb = *(const float2*)(bias + HIDDEN + cq);
    float2 vv = *(const float2*)(cr + 2 * HIDDEN + cq);
    float2 vb = *(const float2*)(bias + 2 * HIDDEN + cq);
    float q0 = qv.x + qb.x, q1 = qv.y + qb.y;
    float k0 = kv.x + kb.x, k1 = kv.y + kb.y;
    float v0 = vv.x + vb.x, v1 = vv.y + vb.y;

    float sq = q0 * q0 + q1 * q1;
    float sk = k0 * k0 + k1 * k1;
#pragma unroll
    for (int off = 1; off < 64; off <<= 1) {
        sq += __shfl_xor(sq, off);
        sk += __shfl_xor(sk, off);
    }
    const float rs_q = rsqrtf(sq * (1.f / HDIM) + 1e-6f);
    const float rs_k = rsqrtf(sk * (1.f / HDIM) + 1e-6f);
    float2 wq = *(const float2*)(rq + 2 * lane);
    float2 wk = *(const float2*)(rk + 2 * lane);
    q0 *= rs_q * wq.x; q1 *= rs_q * wq.y;
    k0 *= rs_k * wk.x; k1 *= rs_k * wk.y;
    float4 f = *(const float4*)(pe + (size_t)pos * 256 + lane * 4);   // (cos,-sin,sin,cos)
    float qo0 = f.x * q0 + f.y * q1, qo1 = f.z * q0 + f.w * q1;
    float ko0 = f.x * k0 + f.y * k1, ko1 = f.z * k0 + f.w * k1;
    size_t ob = (size_t)pos * HIDDEN + h * HDIM + 2 * lane;
    bf16x2 qp; qp[0] = (bf16)qo0; qp[1] = (bf16)qo1;
    bf16x2 kp; kp[0] = (bf16)ko0; kp[1] = (bf16)ko1;
    bf16x2 vp; vp[0] = (bf16)v0;  vp[1] = (bf16)v1;
    *(bf16x2*)(qc + ob) = qp;
    *(bf16x2*)(kc + ob) = kp;
    *(bf16x2*)(vc + ob) = vp;
}

// ---------------------------------------------------------------- flash attention
// grid (SEQL/64, NHEADS); 4 waves; wave owns 16 Q rows; 32-pos KV tiles.
__global__ __launch_bounds__(256) void flash_attn(const bf16* __restrict__ Q,
                                                  const bf16* __restrict__ Kc,
                                                  const bf16* __restrict__ VT,
                                                  bf16* __restrict__ O)
{
    __shared__ bf16 Ks[32 * 128];    // [pos][dim]
    __shared__ bf16 Vs[128 * 32];    // [dim][pos]  (from pre-transposed VT)
    __shared__ bf16 Ps[4][16 * 32];  // per-wave P round-trip (C-layout -> A-layout)
    const int t = threadIdx.x, wave = t >> 6, lane = t & 63;
    const int lm = lane & 15, lq = lane >> 4;
    const int h = blockIdx.y, q0 = blockIdx.x * 64;
    const int hb = h * HDIM;
    const float scale = 0.088388347648318447f;   // 1/sqrt(128)

    bf16x8 qf[4];
    {
        const int qrow = q0 + wave * 16 + lm;
#pragma unroll
        for (int kf = 0; kf < 4; ++kf)
            qf[kf] = *(const bf16x8*)(Q + (size_t)qrow * HIDDEN + hb + kf * 32 + lq * 8);
    }
    f32x4 o[8];
#pragma unroll
    for (int d = 0; d < 8; ++d) o[d] = (f32x4){0.f, 0.f, 0.f, 0.f};
    float mrow[4] = {-1e30f, -1e30f, -1e30f, -1e30f};
    float lrow[4] = {0.f, 0.f, 0.f, 0.f};

    for (int k0 = 0; k0 < SEQL; k0 += 32) {
        {
            const int f0 = t * 8, f1 = 2048 + t * 8;
            async_copy16(Kc + (size_t)(k0 + (f0 >> 7)) * HIDDEN + hb + (f0 & 127), Ks + wave * 512);
            async_copy16(Kc + (size_t)(k0 + (f1 >> 7)) * HIDDEN + hb + (f1 & 127), Ks + 2048 + wave * 512);
            async_copy16(VT + (size_t)(hb + (f0 >> 5)) * SEQL + k0 + (f0 & 31), Vs + wave * 512);
            async_copy16(VT + (size_t)(hb + (f1 >> 5)) * SEQL + k0 + (f1 & 31), Vs + 2048 + wave * 512);
        }
        __syncthreads();

        f32x4 sv[2];
#pragma unroll
        for (int n = 0; n < 2; ++n) {
            f32x4 s = (f32x4){0.f, 0.f, 0.f, 0.f};
#pragma unroll
            for (int kf = 0; kf < 4; ++kf) {
                bf16x8 kfr = *(const bf16x8*)(Ks + (n * 16 + lm) * 128 + kf * 32 + lq * 8);
                s = __builtin_amdgcn_mfma_f32_16x16x32_bf16(qf[kf], kfr, s, 0, 0, 0);
            }
            sv[n] = s;
        }
        float alpha[4], p0v[4], p1v[4];
#pragma unroll
        for (int r = 0; r < 4; ++r) {
            float s0 = sv[0][r] * scale, s1 = sv[1][r] * scale;
            float mx = fmaxf(s0, s1);
            mx = fmaxf(mx, __shfl_xor(mx, 1));
            mx = fmaxf(mx, __shfl_xor(mx, 2));
            mx = fmaxf(mx, __shfl_xor(mx, 4));
            mx = fmaxf(mx, __shfl_xor(mx, 8));
            float mnew = fmaxf(mrow[r], mx);
            alpha[r] = __expf(mrow[r] - mnew);
            mrow[r] = mnew;
            float p0 = __expf(s0 - mnew), p1 = __expf(s1 - mnew);
            float ps = p0 + p1;
            ps += __shfl_xor(ps, 1);
            ps += __shfl_xor(ps, 2);
            ps += __shfl_xor(ps, 4);
            ps += __shfl_xor(ps, 8);
            lrow[r] = lrow[r] * alpha[r] + ps;
            p0v[r] = p0; p1v[r] = p1;
        }
#pragma unroll
        for (int d = 0; d < 8; ++d) {
            o[d][0] *= alpha[0]; o[d][1] *= alpha[1];
            o[d][2] *= alpha[2]; o[d][3] *= alpha[3];
        }
        bf16* pw = &Ps[wave][0];
#pragma unroll
        for (int r = 0; r < 4; ++r) {
            pw[(lq * 4 + r) * 32 + lm]      = (bf16)p0v[r];
            pw[(lq * 4 + r) * 32 + 16 + lm] = (bf16)p1v[r];
        }
        bf16x8 pf = *(const bf16x8*)(pw + lm * 32 + lq * 8);   // A-layout read
#pragma unroll
        for (int d = 0; d < 8; ++d) {
            bf16x8 vf = *(const bf16x8*)(Vs + (d * 16 + lm) * 32 + lq * 8);
            o[d] = __builtin_amdgcn_mfma_f32_16x16x32_bf16(pf, vf, o[d], 0, 0, 0);
        }
        __syncthreads();
    }
#pragma unroll
    for (int d = 0; d < 8; ++d)
#pragma unroll
        for (int r = 0; r < 4; ++r) {
            int orow = q0 + wave * 16 + lq * 4 + r;
            int ocol = hb + d * 16 + lm;
            O[(size_t)orow * HIDDEN + ocol] = (bf16)(o[d][r] / lrow[r]);
        }
}

// ---------------------------------------------------------------- epilogues
__global__ __launch_bounds__(256) void proj_finish(const float* __restrict__ C,
                                                   const float* __restrict__ xin,
                                                   const float* __restrict__ b,
                                                   const float* __restrict__ g,
                                                   float* __restrict__ xout)
{
    const int idx = blockIdx.x * 256 + threadIdx.x;   // over l*768
    const int i = idx / 768, j4 = (idx - i * 768) * 4;
    const float4 c  = *(const float4*)(C + (size_t)i * HIDDEN + j4);
    const float4 bb = *(const float4*)(b + j4);
    const float4 gg = *(const float4*)(g + j4);
    const float4 xx = *(const float4*)(xin + (size_t)i * HIDDEN + j4);
    float4 o;
    o.x = xx.x + gg.x * (c.x + bb.x);
    o.y = xx.y + gg.y * (c.y + bb.y);
    o.z = xx.z + gg.z * (c.z + bb.z);
    o.w = xx.w + gg.w * (c.w + bb.w);
    *(float4*)(xout + (size_t)i * HIDDEN + j4) = o;
}

__global__ __launch_bounds__(256) void mlp0_finish(const float* __restrict__ C,
                                                   const float* __restrict__ b,
                                                   bf16* __restrict__ h)
{
    const int idx = blockIdx.x * 256 + threadIdx.x;   // over l*(MLPD/4)
    const int i = idx / (MLPD / 4), j4 = (idx - i * (MLPD / 4)) * 4;
    const float4 c  = *(const float4*)(C + (size_t)i * MLPD + j4);
    const float4 bb = *(const float4*)(b + j4);
    bf16x4 o;
    o[0] = (bf16)gelu_tanh(c.x + bb.x);
    o[1] = (bf16)gelu_tanh(c.y + bb.y);
    o[2] = (bf16)gelu_tanh(c.z + bb.z);
    o[3] = (bf16)gelu_tanh(c.w + bb.w);
    *(bf16x4*)(h + (size_t)i * MLPD + j4) = o;
}

__global__ __launch_bounds__(256) void mlp2_finish(const float* __restrict__ C,
                                                   const float* __restrict__ x,
                                                   const float* __restrict__ b,
                                                   const float* __restrict__ g,
                                                   float* __restrict__ outp)
{
    const int idx = blockIdx.x * 256 + threadIdx.x;   // over l*768
    const int i = idx / 768, j4 = (idx - i * 768) * 4;
    const float4 c  = *(const float4*)(C + (size_t)i * HIDDEN + j4);
    const float4 bb = *(const float4*)(b + j4);
    const float4 gg = *(const float4*)(g + j4);
    const float4 xx = *(const float4*)(x + (size_t)i * HIDDEN + j4);
    float4 o;
    o.x = xx.x + gg.x * (c.x + bb.x);
    o.y = xx.y + gg.y * (c.y + bb.y);
    o.z = xx.z + gg.z * (c.z + bb.z);
    o.w = xx.w + gg.w * (c.w + bb.w);
    *(float4*)(outp + (size_t)i * HIDDEN + j4) = o;
}

// ---------------------------------------------------------------- launch
extern "C" void kernel_launch(void* const* d_in, const int* in_sizes, int n_in,
                              void* d_out, int out_size, void* d_ws, size_t ws_size,
                              hipStream_t stream)
{
    (void)in_sizes; (void)n_in; (void)out_size; (void)ws_size;
    const float* img     = (const float*)d_in[0];
    const float* txt     = (const float*)d_in[1];
    const float* vec     = (const float*)d_in[2];
    const float* pe      = (const float*)d_in[3];
    const float* mod_w   = (const float*)d_in[4];
    const float* mod_b   = (const float*)d_in[5];
    const float* qkv_w   = (const float*)d_in[6];
    const float* qkv_b   = (const float*)d_in[7];
    const float* qkv_ld  = (const float*)d_in[8];
    const float* qkv_lu  = (const float*)d_in[9];
    const float* rmsq_w  = (const float*)d_in[10];
    const float* rmsk_w  = (const float*)d_in[11];
    const float* proj_w  = (const float*)d_in[12];
    const float* proj_b  = (const float*)d_in[13];
    const float* proj_ld = (const float*)d_in[14];
    const float* proj_lu = (const float*)d_in[15];
    const float* mlp0_w  = (const float*)d_in[16];
    const float* mlp0_b  = (const float*)d_in[17];
    const float* mlp0_ld = (const float*)d_in[18];
    const float* mlp0_lu = (const float*)d_in[19];
    const float* mlp2_w  = (const float*)d_in[20];
    const float* mlp2_b  = (const float*)d_in[21];
    const float* mlp2_ld = (const float*)d_in[22];
    const float* mlp2_lu = (const float*)d_in[23];
    float* outp = (float*)d_out;

    char* wp = (char*)d_ws;
    auto alloc = [&](size_t bytes) {
        void* p = (void*)wp;
        wp += (bytes + 255) & ~(size_t)255;
        return p;
    };
    float* mods  = (float*)alloc(2 * 18432 * sizeof(float));
    bf16*  xm    = (bf16*) alloc((size_t)IMGL * HIDDEN * 2);
    bf16*  Tb    = (bf16*) alloc((size_t)IMGL * RANK * 2);
    float* Tpart = (float*)alloc((size_t)IMGL * RANK * 4 * sizeof(float));
    float* Cb    = (float*)alloc((size_t)IMGL * MLPD * sizeof(float));
    float* luT   = (float*)alloc((size_t)MLPD * RANK * sizeof(float));
    bf16*  qcat  = (bf16*) alloc((size_t)SEQL * HIDDEN * 2);
    bf16*  kcat  = (bf16*) alloc((size_t)SEQL * HIDDEN * 2);
    bf16*  vcat  = (bf16*) alloc((size_t)SEQL * HIDDEN * 2);
    bf16*  vT    = (bf16*) alloc((size_t)SEQL * HIDDEN * 2);
    bf16*  attn  = (bf16*) alloc((size_t)SEQL * HIDDEN * 2);
    float* ximg  = (float*)alloc((size_t)IMGL * HIDDEN * sizeof(float));
    float* xtxt  = (float*)alloc((size_t)TXTL * HIDDEN * sizeof(float));
    bf16*  hbuf  = (bf16*) alloc((size_t)IMGL * MLPD * 2);

    // 1. modulation vectors
    mod_gemv<<<dim3(36864 / 4), 256, 0, stream>>>(vec, mod_w, mod_b, mods);

    // Phase A: per-stream qkv (s=0 img, s=1 txt)
    for (int s = 0; s < 2; ++s) {
        const int l = (s == 0) ? IMGL : TXTL;
        const float* xsrc = (s == 0) ? img : txt;
        const int pos0 = (s == 0) ? TXTL : 0;
        const float* ms = mods + s * 18432;     // [sh1, sc1, g1, sh2, sc2, g2] * HIDDEN
        ln_mod_k<<<dim3(l), 256, 0, stream>>>(xsrc, ms + HIDDEN, ms, xm);
        lora_down<<<dim3(l / 8, 4), 256, 0, stream>>>(xm, qkv_ld + (size_t)s * HIDDEN * RANK, Tpart, HIDDEN, l);
        lora_reduce<<<dim3(l * RANK / 256), 256, 0, stream>>>(Tpart, Tb, l * RANK);
        gemm_bt<false><<<dim3(3 * HIDDEN / 128, l / 128), 256, 0, stream>>>(
            xm, qkv_w + (size_t)s * 3 * HIDDEN * HIDDEN, Cb, l, 3 * HIDDEN, HIDDEN);
        transpose_lu<<<dim3(3 * HIDDEN / 256), 256, 0, stream>>>(qkv_lu + (size_t)s * RANK * 3 * HIDDEN, luT, 3 * HIDDEN);
        gemm_bt<true><<<dim3(3 * HIDDEN / 128, l / 128), 256, 0, stream>>>(Tb, luT, Cb, l, 3 * HIDDEN, RANK);
        qkv_finish<<<dim3(l * NHEADS / 4), 256, 0, stream>>>(
            Cb, qkv_b + (size_t)s * 3 * HIDDEN, rmsq_w + s * HDIM, rmsk_w + s * HDIM,
            pe, qcat, kcat, vcat, pos0);
    }

    // Phase B: attention over concat sequence
    transpose_v<<<dim3(HIDDEN / 64, SEQL / 64), 256, 0, stream>>>(vcat, vT, SEQL, HIDDEN);
    flash_attn<<<dim3(SEQL / 64, NHEADS), 256, 0, stream>>>(qcat, kcat, vT, attn);

    // Phase C: per-stream proj + MLP
    for (int s = 0; s < 2; ++s) {
        const int l = (s == 0) ? IMGL : TXTL;
        const float* xsrc = (s == 0) ? img : txt;
        float* xbuf = (s == 0) ? ximg : xtxt;
        const int pos0 = (s == 0) ? TXTL : 0;
        const float* ms = mods + s * 18432;
        const bf16* a = attn + (size_t)pos0 * HIDDEN;
        // proj
        lora_down<<<dim3(l / 8, 4), 256, 0, stream>>>(a, proj_ld + (size_t)s * HIDDEN * RANK, Tpart, HIDDEN, l);
        lora_reduce<<<dim3(l * RANK / 256), 256, 0, stream>>>(Tpart, Tb, l * RANK);
        gemm_bt<false><<<dim3(HIDDEN / 128, l / 128), 256, 0, stream>>>(
            a, proj_w + (size_t)s * HIDDEN * HIDDEN, Cb, l, HIDDEN, HIDDEN);
        transpose_lu<<<dim3(HIDDEN / 256), 256, 0, stream>>>(proj_lu + (size_t)s * RANK * HIDDEN, luT, HIDDEN);
        gemm_bt<true><<<dim3(HIDDEN / 128, l / 128), 256, 0, stream>>>(Tb, luT, Cb, l, HIDDEN, RANK);
        proj_finish<<<dim3(l * 768 / 256), 256, 0, stream>>>(Cb, xsrc, proj_b + (size_t)s * HIDDEN, ms + 2 * HIDDEN, xbuf);
        // mlp0
        ln_mod_k<<<dim3(l), 256, 0, stream>>>(xbuf, ms + 4 * HIDDEN, ms + 3 * HIDDEN, xm);
        lora_down<<<dim3(l / 8, 4), 256, 0, stream>>>(xm, mlp0_ld + (size_t)s * HIDDEN * RANK, Tpart, HIDDEN, l);
        lora_reduce<<<dim3(l * RANK / 256), 256, 0, stream>>>(Tpart, Tb, l * RANK);
        gemm_bt<false><<<dim3(MLPD / 128, l / 128), 256, 0, stream>>>(
            xm, mlp0_w + (size_t)s * MLPD * HIDDEN, Cb, l, MLPD, HIDDEN);
        transpose_lu<<<dim3(MLPD / 256), 256, 0, stream>>>(mlp0_lu + (size_t)s * RANK * MLPD, luT, MLPD);
        gemm_bt<true><<<dim3(MLPD / 128, l / 128), 256, 0, stream>>>(Tb, luT, Cb, l, MLPD, RANK);
        mlp0_finish<<<dim3(l * (MLPD / 4) / 256), 256, 0, stream>>>(Cb, mlp0_b + (size_t)s * MLPD, hbuf);
        // mlp2
        lora_down<<<dim3(l / 8, 4), 256, 0, stream>>>(hbuf, mlp2_ld + (size_t)s * MLPD * RANK, Tpart, MLPD, l);
        lora_reduce<<<dim3(l * RANK / 256), 256, 0, stream>>>(Tpart, Tb, l * RANK);
        gemm_bt<false><<<dim3(HIDDEN / 128, l / 128), 256, 0, stream>>>(
            hbuf, mlp2_w + (size_t)s * HIDDEN * MLPD, Cb, l, HIDDEN, MLPD);
        transpose_lu<<<dim3(HIDDEN / 256), 256, 0, stream>>>(mlp2_lu + (size_t)s * RANK * HIDDEN, luT, HIDDEN);
        gemm_bt<true><<<dim3(HIDDEN / 128, l / 128), 256, 0, stream>>>(Tb, luT, Cb, l, HIDDEN, RANK);
        mlp2_finish<<<dim3(l * 768 / 256), 256, 0, stream>>>(Cb, xbuf, mlp2_b + (size_t)s * HIDDEN, ms + 5 * HIDDEN, outp + (size_t)pos0 * HIDDEN);
    }
}